// Round 6
// baseline (285.995 us; speedup 1.0000x reference)
//
#include <hip/hip_runtime.h>
#include <hip/hip_fp16.h>

#define B_ 64
#define T_ 2048
#define D_ 256
#define U_ 256
#define RB 128            // T rows per score block (4 rounds of 32)
#define NTB (T_ / RB)     // 16 score blocks per batch
#define CC 8              // context chunks per batch (256 rows each)

typedef _Float16 half8  __attribute__((ext_vector_type(8)));
typedef float    floatx4 __attribute__((ext_vector_type(4)));

// ---------------- Kernel 1 (fused prep): qproj (blocks 0..63) + w2t (blocks 64..127) ----------
__global__ void prep_kernel(const float* __restrict__ query,
                            const float* __restrict__ W1_w,
                            const float* __restrict__ W1_b,
                            const float* __restrict__ W2_w,
                            const float* __restrict__ W2_b,
                            float* __restrict__ qb,
                            _Float16* __restrict__ w2t) {
    __shared__ float sh[32 * 33];
    if (blockIdx.x < 64) {
        const int b = blockIdx.x;
        const int u = threadIdx.x;           // 256 threads
        sh[u] = query[b * D_ + u];
        __syncthreads();
        float acc = W1_b[u] + W2_b[u];
#pragma unroll 8
        for (int d = 0; d < D_; ++d)
            acc += sh[d] * W1_w[d * U_ + u];
        qb[b * U_ + u] = acc;
    } else {
        const int bid = blockIdx.x - 64;
        const int tu = bid & 7;
        const int td = bid >> 3;
        const int c  = threadIdx.x & 31;
        const int r0 = threadIdx.x >> 5;
        float* tile = sh;                    // [32][33]
#pragma unroll
        for (int i = 0; i < 4; ++i) {
            int r = r0 + i * 8;
            tile[r * 33 + c] = W2_w[(td * 32 + r) * U_ + tu * 32 + c];
        }
        __syncthreads();
#pragma unroll
        for (int i = 0; i < 4; ++i) {
            int r = r0 + i * 8;              // u within tile
            w2t[(tu * 32 + r) * D_ + td * 32 + c] = (_Float16)tile[c * 33 + r];
        }
    }
}

// ---------------- Kernel 2: pure score GEMM -> w = exp(score) ----------------
// Grid (16, 64): block = 128 T-rows x 256 U, K=256. 512 thr = 8 waves; wave w owns
// u in [w*32, w*32+32): bfrag = 2nt x 8ks x half8 = 64 regs AGPR-pinned (R5-proven),
// amortized over 128 rows. 4 rounds of 32 rows; A staged f32->f16 through VGPRs with
// a software pipeline (round r+1's global loads issued before round r's MFMA), LDS
// double-buffered -> ONE barrier per round. Epilogue butterfly once per 32 rows.
// A-tile LDS layout: 16B chunk c of row r stored at chunk c ^ (r&7) (conflict-spread
// for both the staging b128 writes and the MFMA b128 A-reads).
// No max-shift: |score| <= ||V_w||_1 ~ 10, exp safe in fp32 (verified R2-R5).
__launch_bounds__(512, 4)
__global__ void score_kernel(const float* __restrict__ values,
                             const _Float16* __restrict__ w2t,
                             const float* __restrict__ qb,
                             const float* __restrict__ V_w,
                             float* __restrict__ wexp,
                             float* __restrict__ pl) {
    __shared__ __align__(16) _Float16 Atile[2][32 * 256];  // 2 x 16KB f16
    __shared__ __align__(16) float s_part[RB][8];          // 4KB
    __shared__ float red2[2];

    const int b    = blockIdx.y;
    const int tb   = blockIdx.x;         // row block: rows tb*128 ..
    const int tid  = threadIdx.x;
    const int wave = tid >> 6;           // 0..7
    const int lane = tid & 63;
    const int n16  = lane & 15;
    const int quad = lane >> 4;
    const int u0   = wave * 32;

    // --- W2 B-fragments: 64 regs, AGPR-pinned (resident; R5 evidence) ---
    half8 bfrag[2][8];
#pragma unroll
    for (int nt = 0; nt < 2; ++nt) {
        const int u = u0 + nt * 16 + n16;
#pragma unroll
        for (int ks = 0; ks < 8; ++ks) {
            bfrag[nt][ks] = *(const half8*)(w2t + u * D_ + ks * 32 + quad * 8);
            asm volatile("" : "+a"(bfrag[nt][ks]));   // force AGPR residence
        }
    }
    float qbv[2], vwv[2];
#pragma unroll
    for (int nt = 0; nt < 2; ++nt) {
        const int u = u0 + nt * 16 + n16;
        qbv[nt] = qb[b * U_ + u];
        vwv[nt] = V_w[u];
    }

    // --- staging map: thread -> (row rl 0..31, part pp 0..15 = 16 k's = 2 chunks) ---
    const int rl = tid >> 4;
    const int pp = tid & 15;
    const float* srow = values + ((size_t)b * T_ + (size_t)tb * RB + rl) * D_ + pp * 16;

    floatx4 sv[4];
#pragma unroll
    for (int i = 0; i < 4; ++i) sv[i] = *(const floatx4*)(srow + i * 4);
    // write round 0
#pragma unroll
    for (int i = 0; i < 2; ++i) {
        half8 h;
        h[0] = (_Float16)sv[2*i].x; h[1] = (_Float16)sv[2*i].y;
        h[2] = (_Float16)sv[2*i].z; h[3] = (_Float16)sv[2*i].w;
        h[4] = (_Float16)sv[2*i+1].x; h[5] = (_Float16)sv[2*i+1].y;
        h[6] = (_Float16)sv[2*i+1].z; h[7] = (_Float16)sv[2*i+1].w;
        const int cp = (2 * pp + i) ^ (rl & 7);
        *(half8*)(&Atile[0][rl * 256 + cp * 8]) = h;
    }

    for (int rnd = 0; rnd < 4; ++rnd) {
        __syncthreads();                 // Atile[rnd&1] staged; old reads done
        if (rnd < 3) {                   // prefetch next round's A into regs (overlaps MFMA)
            const float* s2 = srow + (size_t)(rnd + 1) * 32 * D_;
#pragma unroll
            for (int i = 0; i < 4; ++i) sv[i] = *(const floatx4*)(s2 + i * 4);
        }

        // --- MFMA: 2 mtiles x 8 ksteps x 2 ntiles ---
        floatx4 acc[2][2] = {};
#pragma unroll
        for (int ks = 0; ks < 8; ++ks) {
#pragma unroll
            for (int mt = 0; mt < 2; ++mt) {
                const int rr = mt * 16 + n16;
                const int cp = (ks * 4 + quad) ^ (n16 & 7);   // rr&7 == n16&7
                half8 a = *(const half8*)(&Atile[rnd & 1][rr * 256 + cp * 8]);
#pragma unroll
                for (int nt = 0; nt < 2; ++nt)
                    acc[mt][nt] = __builtin_amdgcn_mfma_f32_16x16x32_f16(a, bfrag[nt][ks], acc[mt][nt], 0, 0, 0);
            }
        }

        // --- epilogue: tanh + dot V_w; butterfly over n16; once per 32 rows ---
        float rs[2][4];
#pragma unroll
        for (int mt = 0; mt < 2; ++mt)
#pragma unroll
            for (int r4 = 0; r4 < 4; ++r4) {
                float s = 0.f;
#pragma unroll
                for (int nt = 0; nt < 2; ++nt) {
                    float x  = acc[mt][nt][r4] + qbv[nt];
                    float e  = __expf(2.f * x);
                    float th = 1.f - __fdividef(2.f, e + 1.f);   // tanh(x)
                    s += th * vwv[nt];
                }
                rs[mt][r4] = s;
            }
#pragma unroll
        for (int m = 1; m < 16; m <<= 1)
#pragma unroll
            for (int mt = 0; mt < 2; ++mt)
#pragma unroll
                for (int r4 = 0; r4 < 4; ++r4)
                    rs[mt][r4] += __shfl_xor(rs[mt][r4], m, 16);
        if (n16 == 0)
#pragma unroll
            for (int mt = 0; mt < 2; ++mt)
#pragma unroll
                for (int r4 = 0; r4 < 4; ++r4)
                    s_part[rnd * 32 + mt * 16 + quad * 4 + r4][wave] = rs[mt][r4];

        // --- write next round's A-tile (other buffer; visible at next barrier) ---
        if (rnd < 3) {
#pragma unroll
            for (int i = 0; i < 2; ++i) {
                half8 h;
                h[0] = (_Float16)sv[2*i].x; h[1] = (_Float16)sv[2*i].y;
                h[2] = (_Float16)sv[2*i].z; h[3] = (_Float16)sv[2*i].w;
                h[4] = (_Float16)sv[2*i+1].x; h[5] = (_Float16)sv[2*i+1].y;
                h[6] = (_Float16)sv[2*i+1].z; h[7] = (_Float16)sv[2*i+1].w;
                const int cp = (2 * pp + i) ^ (rl & 7);
                *(half8*)(&Atile[(rnd + 1) & 1][rl * 256 + cp * 8]) = h;
            }
        }
    }

    __syncthreads();
    if (tid < RB) {
        floatx4 p0 = *(const floatx4*)&s_part[tid][0];
        floatx4 p1 = *(const floatx4*)&s_part[tid][4];
        float s = ((p0.x + p0.y) + (p0.z + p0.w)) + ((p1.x + p1.y) + (p1.z + p1.w));
        float w = __expf(s);
        wexp[b * T_ + tb * RB + tid] = w;
        float ls = w;
#pragma unroll
        for (int m = 1; m < 64; m <<= 1) ls += __shfl_xor(ls, m, 64);
        if (lane == 0) red2[wave] = ls;       // tid<128 -> waves 0,1
    }
    __syncthreads();
    if (tid == 0) pl[b * NTB + tb] = red2[0] + red2[1];
}

// ---------------- Kernel 3: context partials (pure stream; R1-proven pattern) ----------------
// grid (CC, B), 256 thr: block streams 256 rows x 256 d with float4, weights in LDS.
__global__ void context_kernel(const float* __restrict__ values,
                               const float* __restrict__ wexp,
                               float* __restrict__ pctx) {
    __shared__ float w[256];
    __shared__ floatx4 part[256];
    const int b  = blockIdx.y;
    const int ch = blockIdx.x;
    const int tid = threadIdx.x;
    w[tid] = wexp[b * T_ + ch * 256 + tid];
    __syncthreads();
    const int r = tid >> 6;            // 0..3
    const int c = tid & 63;            // float4 column
    const float* vb = values + ((size_t)b * T_ + (size_t)ch * 256) * D_;
    floatx4 acc = {0.f, 0.f, 0.f, 0.f};
#pragma unroll 4
    for (int i = 0; i < 64; ++i) {
        const int t = i * 4 + r;
        acc += *(const floatx4*)(vb + t * D_ + c * 4) * w[t];
    }
    part[tid] = acc;
    __syncthreads();
    if (tid < 64) {
        floatx4 s = part[tid] + part[tid + 64] + part[tid + 128] + part[tid + 192];
        *(floatx4*)(pctx + ((size_t)b * CC + ch) * D_ + tid * 4) = s;
    }
}

// ---------------- Kernel 4: combine partials -> ctx, attn ----------------
__global__ void finalize_kernel(const float* __restrict__ pctx,
                                const float* __restrict__ pl,
                                const float* __restrict__ wexp,
                                float* __restrict__ ctx,
                                float* __restrict__ attn) {
    const int b = blockIdx.x, tid = threadIdx.x;   // 256 threads
    float L = 0.f;
#pragma unroll
    for (int i = 0; i < NTB; ++i) L += pl[b * NTB + i];
    const float invL = 1.f / L;
    float s = 0.f;
#pragma unroll
    for (int i = 0; i < CC; ++i) s += pctx[(b * CC + i) * D_ + tid];
    ctx[b * D_ + tid] = s * invL;
#pragma unroll
    for (int j = 0; j < T_ / 256; ++j) {
        const int t = j * 256 + tid;
        attn[b * T_ + t] = wexp[b * T_ + t] * invL;
    }
}

extern "C" void kernel_launch(void* const* d_in, const int* in_sizes, int n_in,
                              void* d_out, int out_size, void* d_ws, size_t ws_size,
                              hipStream_t stream) {
    const float* query  = (const float*)d_in[0];
    const float* values = (const float*)d_in[1];
    const float* W1_w   = (const float*)d_in[2];
    const float* W1_b   = (const float*)d_in[3];
    const float* W2_w   = (const float*)d_in[4];
    const float* W2_b   = (const float*)d_in[5];
    const float* V_w    = (const float*)d_in[6];
    // d_in[7] = V_b: softmax is shift-invariant -> no effect on either output.

    float* out  = (float*)d_out;
    float* ctx  = out;                  // [B, D]
    float* attn = out + B_ * D_;        // [B, T]

    char* ws = (char*)d_ws;
    float*    qb   = (float*)ws;                                 // B*U fp32      (64 KB)
    _Float16* w2t  = (_Float16*)(ws + (64 << 10));               // U*D fp16      (128 KB)
    float*    wexp = (float*)(ws + (192 << 10));                 // B*T fp32      (512 KB)
    float*    pctx = (float*)(ws + (704 << 10));                 // B*CC*D fp32   (512 KB)
    float*    pl   = (float*)(ws + (1216 << 10));                // B*NTB fp32    (4 KB)

    prep_kernel    <<<dim3(128),      dim3(256), 0, stream>>>(query, W1_w, W1_b, W2_w, W2_b, qb, w2t);
    score_kernel   <<<dim3(NTB, B_),  dim3(512), 0, stream>>>(values, w2t, qb, V_w, wexp, pl);
    context_kernel <<<dim3(CC, B_),   dim3(256), 0, stream>>>(values, wexp, pctx);
    finalize_kernel<<<dim3(B_),       dim3(256), 0, stream>>>(pctx, pl, wexp, ctx, attn);
}

// Round 7
// 270.077 us; speedup vs baseline: 1.0589x; 1.0589x over previous
//
#include <hip/hip_runtime.h>
#include <hip/hip_fp16.h>

#define B_ 64
#define T_ 2048
#define D_ 256
#define U_ 256
#define RB 128            // T rows per score block (4 rounds of 32)
#define NTB (T_ / RB)     // 16 score blocks per batch
#define CC 8              // context chunks per batch (256 rows each)

typedef _Float16 half8  __attribute__((ext_vector_type(8)));
typedef float    floatx4 __attribute__((ext_vector_type(4)));

// ---------------- Kernel 1 (fused prep): qproj (blocks 0..63) + w2t (blocks 64..127) ----------
__global__ void prep_kernel(const float* __restrict__ query,
                            const float* __restrict__ W1_w,
                            const float* __restrict__ W1_b,
                            const float* __restrict__ W2_w,
                            const float* __restrict__ W2_b,
                            float* __restrict__ qb,
                            _Float16* __restrict__ w2t) {
    __shared__ float sh[32 * 33];
    if (blockIdx.x < 64) {
        const int b = blockIdx.x;
        const int u = threadIdx.x;           // 256 threads
        sh[u] = query[b * D_ + u];
        __syncthreads();
        float acc = W1_b[u] + W2_b[u];
#pragma unroll 8
        for (int d = 0; d < D_; ++d)
            acc += sh[d] * W1_w[d * U_ + u];
        qb[b * U_ + u] = acc;
    } else {
        const int bid = blockIdx.x - 64;
        const int tu = bid & 7;
        const int td = bid >> 3;
        const int c  = threadIdx.x & 31;
        const int r0 = threadIdx.x >> 5;
        float* tile = sh;                    // [32][33]
#pragma unroll
        for (int i = 0; i < 4; ++i) {
            int r = r0 + i * 8;
            tile[r * 33 + c] = W2_w[(td * 32 + r) * U_ + tu * 32 + c];
        }
        __syncthreads();
#pragma unroll
        for (int i = 0; i < 4; ++i) {
            int r = r0 + i * 8;              // u within tile
            w2t[(tu * 32 + r) * D_ + td * 32 + c] = (_Float16)tile[c * 33 + r];
        }
    }
}

// ---------------- Kernel 2: pure score GEMM -> w = exp(score) ----------------
// Grid (16, 64): block = 128 T-rows x 256 U, K=256. 512 thr = 8 waves; wave w owns
// u in [w*32, w*32+32): bfrag = 2nt x 8ks x half8 = 64 regs AGPR-pinned, amortized
// over 128 rows. 4 rounds of 32 rows; A staged f32->f16 through VGPRs with a software
// pipeline (round r+1's global loads issued before round r's MFMA), LDS double-buffered
// -> ONE barrier per round. Epilogue butterfly once per 32 rows.
// REGISTER BUDGET (the R1-R6 recurring disease): demand = 64 AGPR (bfrag) + ~86 VGPR
// = ~150 combined. launch_bounds(512,4) caps at 128 -> 24-reg scratch spill (R6:
// WRITE_SIZE 49.7MB). (512,3) caps ~170 -> fits, zero spill (R5: 84 VGPR + 64 AGPR,
// WRITE 1MB). DO NOT tighten this bound without re-checking WRITE_SIZE.
// No max-shift: |score| <= ||V_w||_1 ~ 10, exp safe in fp32 (verified R2-R6).
__launch_bounds__(512, 3)
__global__ void score_kernel(const float* __restrict__ values,
                             const _Float16* __restrict__ w2t,
                             const float* __restrict__ qb,
                             const float* __restrict__ V_w,
                             float* __restrict__ wexp,
                             float* __restrict__ pl) {
    __shared__ __align__(16) _Float16 Atile[2][32 * 256];  // 2 x 16KB f16
    __shared__ __align__(16) float s_part[RB][8];          // 4KB
    __shared__ float red2[2];

    const int b    = blockIdx.y;
    const int tb   = blockIdx.x;         // row block: rows tb*128 ..
    const int tid  = threadIdx.x;
    const int wave = tid >> 6;           // 0..7
    const int lane = tid & 63;
    const int n16  = lane & 15;
    const int quad = lane >> 4;
    const int u0   = wave * 32;

    // --- W2 B-fragments: 64 regs, AGPR-pinned (resident; R5 evidence) ---
    half8 bfrag[2][8];
#pragma unroll
    for (int nt = 0; nt < 2; ++nt) {
        const int u = u0 + nt * 16 + n16;
#pragma unroll
        for (int ks = 0; ks < 8; ++ks) {
            bfrag[nt][ks] = *(const half8*)(w2t + u * D_ + ks * 32 + quad * 8);
            asm volatile("" : "+a"(bfrag[nt][ks]));   // force AGPR residence
        }
    }
    float qbv[2], vwv[2];
#pragma unroll
    for (int nt = 0; nt < 2; ++nt) {
        const int u = u0 + nt * 16 + n16;
        qbv[nt] = qb[b * U_ + u];
        vwv[nt] = V_w[u];
    }

    // --- staging map: thread -> (row rl 0..31, part pp 0..15 = 16 k's = 2 chunks) ---
    const int rl = tid >> 4;
    const int pp = tid & 15;
    const float* srow = values + ((size_t)b * T_ + (size_t)tb * RB + rl) * D_ + pp * 16;

    floatx4 sv[4];
#pragma unroll
    for (int i = 0; i < 4; ++i) sv[i] = *(const floatx4*)(srow + i * 4);
    // write round 0
#pragma unroll
    for (int i = 0; i < 2; ++i) {
        half8 h;
        h[0] = (_Float16)sv[2*i].x; h[1] = (_Float16)sv[2*i].y;
        h[2] = (_Float16)sv[2*i].z; h[3] = (_Float16)sv[2*i].w;
        h[4] = (_Float16)sv[2*i+1].x; h[5] = (_Float16)sv[2*i+1].y;
        h[6] = (_Float16)sv[2*i+1].z; h[7] = (_Float16)sv[2*i+1].w;
        const int cp = (2 * pp + i) ^ (rl & 7);
        *(half8*)(&Atile[0][rl * 256 + cp * 8]) = h;
    }

    for (int rnd = 0; rnd < 4; ++rnd) {
        __syncthreads();                 // Atile[rnd&1] staged; old reads done
        if (rnd < 3) {                   // prefetch next round's A into regs (overlaps MFMA)
            const float* s2 = srow + (size_t)(rnd + 1) * 32 * D_;
#pragma unroll
            for (int i = 0; i < 4; ++i) sv[i] = *(const floatx4*)(s2 + i * 4);
        }

        // --- MFMA: 2 mtiles x 8 ksteps x 2 ntiles ---
        floatx4 acc[2][2] = {};
#pragma unroll
        for (int ks = 0; ks < 8; ++ks) {
#pragma unroll
            for (int mt = 0; mt < 2; ++mt) {
                const int rr = mt * 16 + n16;
                const int cp = (ks * 4 + quad) ^ (n16 & 7);   // rr&7 == n16&7
                half8 a = *(const half8*)(&Atile[rnd & 1][rr * 256 + cp * 8]);
#pragma unroll
                for (int nt = 0; nt < 2; ++nt)
                    acc[mt][nt] = __builtin_amdgcn_mfma_f32_16x16x32_f16(a, bfrag[nt][ks], acc[mt][nt], 0, 0, 0);
            }
        }

        // --- epilogue: tanh + dot V_w; butterfly over n16; once per 32 rows ---
        float rs[2][4];
#pragma unroll
        for (int mt = 0; mt < 2; ++mt)
#pragma unroll
            for (int r4 = 0; r4 < 4; ++r4) {
                float s = 0.f;
#pragma unroll
                for (int nt = 0; nt < 2; ++nt) {
                    float x  = acc[mt][nt][r4] + qbv[nt];
                    float e  = __expf(2.f * x);
                    float th = 1.f - __fdividef(2.f, e + 1.f);   // tanh(x)
                    s += th * vwv[nt];
                }
                rs[mt][r4] = s;
            }
#pragma unroll
        for (int m = 1; m < 16; m <<= 1)
#pragma unroll
            for (int mt = 0; mt < 2; ++mt)
#pragma unroll
                for (int r4 = 0; r4 < 4; ++r4)
                    rs[mt][r4] += __shfl_xor(rs[mt][r4], m, 16);
        if (n16 == 0)
#pragma unroll
            for (int mt = 0; mt < 2; ++mt)
#pragma unroll
                for (int r4 = 0; r4 < 4; ++r4)
                    s_part[rnd * 32 + mt * 16 + quad * 4 + r4][wave] = rs[mt][r4];

        // --- write next round's A-tile (other buffer; visible at next barrier) ---
        if (rnd < 3) {
#pragma unroll
            for (int i = 0; i < 2; ++i) {
                half8 h;
                h[0] = (_Float16)sv[2*i].x; h[1] = (_Float16)sv[2*i].y;
                h[2] = (_Float16)sv[2*i].z; h[3] = (_Float16)sv[2*i].w;
                h[4] = (_Float16)sv[2*i+1].x; h[5] = (_Float16)sv[2*i+1].y;
                h[6] = (_Float16)sv[2*i+1].z; h[7] = (_Float16)sv[2*i+1].w;
                const int cp = (2 * pp + i) ^ (rl & 7);
                *(half8*)(&Atile[(rnd + 1) & 1][rl * 256 + cp * 8]) = h;
            }
        }
    }

    __syncthreads();
    if (tid < RB) {
        floatx4 p0 = *(const floatx4*)&s_part[tid][0];
        floatx4 p1 = *(const floatx4*)&s_part[tid][4];
        float s = ((p0.x + p0.y) + (p0.z + p0.w)) + ((p1.x + p1.y) + (p1.z + p1.w));
        float w = __expf(s);
        wexp[b * T_ + tb * RB + tid] = w;
        float ls = w;
#pragma unroll
        for (int m = 1; m < 64; m <<= 1) ls += __shfl_xor(ls, m, 64);
        if (lane == 0) red2[wave] = ls;       // tid<128 -> waves 0,1
    }
    __syncthreads();
    if (tid == 0) pl[b * NTB + tb] = red2[0] + red2[1];
}

// ---------------- Kernel 3: context partials (pure stream; R1-proven pattern) ----------------
// grid (CC, B), 256 thr: block streams 256 rows x 256 d with float4, weights in LDS.
__global__ void context_kernel(const float* __restrict__ values,
                               const float* __restrict__ wexp,
                               float* __restrict__ pctx) {
    __shared__ float w[256];
    __shared__ floatx4 part[256];
    const int b  = blockIdx.y;
    const int ch = blockIdx.x;
    const int tid = threadIdx.x;
    w[tid] = wexp[b * T_ + ch * 256 + tid];
    __syncthreads();
    const int r = tid >> 6;            // 0..3
    const int c = tid & 63;            // float4 column
    const float* vb = values + ((size_t)b * T_ + (size_t)ch * 256) * D_;
    floatx4 acc = {0.f, 0.f, 0.f, 0.f};
#pragma unroll 4
    for (int i = 0; i < 64; ++i) {
        const int t = i * 4 + r;
        acc += *(const floatx4*)(vb + t * D_ + c * 4) * w[t];
    }
    part[tid] = acc;
    __syncthreads();
    if (tid < 64) {
        floatx4 s = part[tid] + part[tid + 64] + part[tid + 128] + part[tid + 192];
        *(floatx4*)(pctx + ((size_t)b * CC + ch) * D_ + tid * 4) = s;
    }
}

// ---------------- Kernel 4: combine partials -> ctx, attn ----------------
__global__ void finalize_kernel(const float* __restrict__ pctx,
                                const float* __restrict__ pl,
                                const float* __restrict__ wexp,
                                float* __restrict__ ctx,
                                float* __restrict__ attn) {
    const int b = blockIdx.x, tid = threadIdx.x;   // 256 threads
    float L = 0.f;
#pragma unroll
    for (int i = 0; i < NTB; ++i) L += pl[b * NTB + i];
    const float invL = 1.f / L;
    float s = 0.f;
#pragma unroll
    for (int i = 0; i < CC; ++i) s += pctx[(b * CC + i) * D_ + tid];
    ctx[b * D_ + tid] = s * invL;
#pragma unroll
    for (int j = 0; j < T_ / 256; ++j) {
        const int t = j * 256 + tid;
        attn[b * T_ + t] = wexp[b * T_ + t] * invL;
    }
}

extern "C" void kernel_launch(void* const* d_in, const int* in_sizes, int n_in,
                              void* d_out, int out_size, void* d_ws, size_t ws_size,
                              hipStream_t stream) {
    const float* query  = (const float*)d_in[0];
    const float* values = (const float*)d_in[1];
    const float* W1_w   = (const float*)d_in[2];
    const float* W1_b   = (const float*)d_in[3];
    const float* W2_w   = (const float*)d_in[4];
    const float* W2_b   = (const float*)d_in[5];
    const float* V_w    = (const float*)d_in[6];
    // d_in[7] = V_b: softmax is shift-invariant -> no effect on either output.

    float* out  = (float*)d_out;
    float* ctx  = out;                  // [B, D]
    float* attn = out + B_ * D_;        // [B, T]

    char* ws = (char*)d_ws;
    float*    qb   = (float*)ws;                                 // B*U fp32      (64 KB)
    _Float16* w2t  = (_Float16*)(ws + (64 << 10));               // U*D fp16      (128 KB)
    float*    wexp = (float*)(ws + (192 << 10));                 // B*T fp32      (512 KB)
    float*    pctx = (float*)(ws + (704 << 10));                 // B*CC*D fp32   (512 KB)
    float*    pl   = (float*)(ws + (1216 << 10));                // B*NTB fp32    (4 KB)

    prep_kernel    <<<dim3(128),      dim3(256), 0, stream>>>(query, W1_w, W1_b, W2_w, W2_b, qb, w2t);
    score_kernel   <<<dim3(NTB, B_),  dim3(512), 0, stream>>>(values, w2t, qb, V_w, wexp, pl);
    context_kernel <<<dim3(CC, B_),   dim3(256), 0, stream>>>(values, wexp, pctx);
    finalize_kernel<<<dim3(B_),       dim3(256), 0, stream>>>(pctx, pl, wexp, ctx, attn);
}